// Round 2
// baseline (343.577 us; speedup 1.0000x reference)
//
#include <hip/hip_runtime.h>
#include <math.h>

// B=2, H=16, S=4096, D=64, W=256. Output (2,4096,16,513) fp32.
#define S_LEN 4096
#define NHEAD 16
#define WI    256
#define NC    513
#define TI    32        // query rows per block (was 64; halves acc VGPRs)
#define CK    96        // keys per LDS chunk
#define NCH   6         // 6*96 = 576 staged span = TI + 2*WI + 32 slack
#define NTW   18        // key tiles of 16 per wave (parity-interleaved)
#define KSTR  72        // LDS row stride in bf16 elems (pad 64->72; conflict-free)
#define PV    (S_LEN * 64)   // elems per p-slice of qr-layout

typedef __attribute__((ext_vector_type(8))) short short8;   // 8 bf16 = 4 VGPRs
typedef __attribute__((ext_vector_type(4))) float floatx4;  // MFMA C/D
typedef float float4u __attribute__((ext_vector_type(4), aligned(4)));  // unaligned-ok store

static __device__ __forceinline__ unsigned short f2bf_rn(float f) {
  unsigned int u = __float_as_uint(f);
  u += 0x7FFFu + ((u >> 16) & 1u);
  return (unsigned short)(u >> 16);
}

// ---- kernel 1: split fp32 x -> hi/lo bf16, permuted to qr layout (p, v, d) ----
// qr[p, v, d] = x[b = p>>4, h = v&15, s = (p&15)*256 + (v>>4), d]
__global__ __launch_bounds__(256)
void split_kernel(const float* __restrict__ x,
                  unsigned short* __restrict__ xh,
                  unsigned short* __restrict__ xl) {
  const int idx = blockIdx.x * 256 + threadIdx.x;   // float4 unit
  const float4 val = ((const float4*)x)[idx];
  const int d4  = idx & 15;
  const int row = idx >> 4;            // (b*16 + h)*4096 + s
  const int s = row & 4095;
  const int h = (row >> 12) & 15;
  const int b = row >> 16;
  const int p = (b << 4) + (s >> 8);
  const int v = ((s & 255) << 4) + h;
  const size_t off = (size_t)p * PV + v * 64 + d4 * 4;
  const unsigned int ux = __float_as_uint(val.x), uy = __float_as_uint(val.y);
  const unsigned int uz = __float_as_uint(val.z), uw = __float_as_uint(val.w);
  ushort4 hi, lo;
  hi.x = ux >> 16; hi.y = uy >> 16; hi.z = uz >> 16; hi.w = uw >> 16;
  lo.x = f2bf_rn(val.x - __uint_as_float(ux & 0xFFFF0000u));
  lo.y = f2bf_rn(val.y - __uint_as_float(uy & 0xFFFF0000u));
  lo.z = f2bf_rn(val.z - __uint_as_float(uz & 0xFFFF0000u));
  lo.w = f2bf_rn(val.w - __uint_as_float(uw & 0xFFFF0000u));
  *(ushort4*)(xh + off) = hi;
  *(ushort4*)(xl + off) = lo;
}

// ---- kernel 2: banded scores + softmax ----
// Swapped-operand MFMA: D[row = key (quad*4+reg)][col = q-row (lane&15)],
// so each lane owns 4 CONSECUTIVE output columns per key tile -> in-lane
// softmax + dwordx4 stores. 4 waves = 2 row-halves x 2 key-parities.
__global__ __launch_bounds__(256, 3)
void attn_kernel(const unsigned short* __restrict__ xh,
                 const unsigned short* __restrict__ xl,
                 float* __restrict__ out) {
  const int t  = threadIdx.x;
  const int id = blockIdx.x;
  // XCD swizzle: id%8 == c handles tiles [16c, 16c+16) of each p (contig L2)
  const int p    = id >> 7;
  const int r7   = id & 127;
  const int tile = ((r7 & 7) << 4) | (r7 >> 3);
  const int i0   = tile * TI;
  const int b    = p >> 4;
  const int hh   = p & 15;
  const int jb   = i0 - 272;           // staged key span [jb, jb+576)
  const int w    = t >> 6;
  const int wr   = w >> 1;             // row half: q rows [wr*16, wr*16+16)
  const int wc   = w & 1;              // key parity: tiles g with (g&1)==wc
  const int quad = (t >> 4) & 3;
  const int n    = t & 15;

  __shared__ unsigned short Qh[TI * KSTR], Ql[TI * KSTR];
  __shared__ unsigned short Kh[CK * KSTR], Kl[CK * KSTR];
  __shared__ float red[2][2][TI];      // [max|sum][wc][row]

  const unsigned short* ph = xh + (size_t)p * PV;
  const unsigned short* pl = xl + (size_t)p * PV;

#define LOAD_CHUNK(mm, dsth, dstl)                                      \
  { _Pragma("unroll")                                                   \
    for (int k = 0; k < 3; ++k) {                                       \
      const int u = t + (k << 8);                                       \
      const int row = u >> 3, col = (u & 7) << 3;                       \
      const int v = jb + (mm) * CK + row;                               \
      short8 zh = {0,0,0,0,0,0,0,0}, zl = {0,0,0,0,0,0,0,0};            \
      if (v >= 0 && v < S_LEN) {                                        \
        zh = *(const short8*)(ph + (size_t)v * 64 + col);               \
        zl = *(const short8*)(pl + (size_t)v * 64 + col);               \
      }                                                                 \
      (dsth)[k] = zh; (dstl)[k] = zl;                                   \
    } }

#define WRITE_CHUNK(srch, srcl)                                         \
  { _Pragma("unroll")                                                   \
    for (int k = 0; k < 3; ++k) {                                       \
      const int u = t + (k << 8);                                       \
      const int row = u >> 3, col = (u & 7) << 3;                       \
      *(short8*)(Kh + row * KSTR + col) = (srch)[k];                    \
      *(short8*)(Kl + row * KSTR + col) = (srcl)[k];                    \
    } }

  short8 pfh[3], pfl[3];    // single-buffer chunk prefetch (WAR is safe:
                            // ds_write consumes regs at issue before reload)
  // ---- stage Q (32 rows, 1 unit/thread) + prefetch K chunk 0 ----
  {
    const int row = t >> 3, col = (t & 7) << 3;
    const short8 qbh = *(const short8*)(ph + (size_t)(i0 + row) * 64 + col);
    const short8 qbl = *(const short8*)(pl + (size_t)(i0 + row) * 64 + col);
    LOAD_CHUNK(0, pfh, pfl);
    *(short8*)(Qh + row * KSTR + col) = qbh;
    *(short8*)(Ql + row * KSTR + col) = qbl;
  }
  __syncthreads();

  // ---- Q fragments (operand B): B[q = lane&15][k = quad*8 + j] ----
  const int arow = (wr * 16 + n) * KSTR + quad * 8;
  const short8 qh0 = *(const short8*)(Qh + arow);
  const short8 qh1 = *(const short8*)(Qh + arow + 32);
  const short8 ql0 = *(const short8*)(Ql + arow);
  const short8 ql1 = *(const short8*)(Ql + arow + 32);

  floatx4 acc[NTW];
#pragma unroll
  for (int jt = 0; jt < NTW; ++jt) acc[jt] = (floatx4){0.f, 0.f, 0.f, 0.f};

  // ---- main loop ----
#pragma unroll
  for (int m = 0; m < NCH; ++m) {
    WRITE_CHUNK(pfh, pfl);
    __syncthreads();
    if (m < NCH - 1) LOAD_CHUNK(m + 1, pfh, pfl);
#pragma unroll
    for (int u = 0; u < 6; ++u) {
      const int g = m * 6 + u;             // global key tile 0..35
      if (g == 0 || g == 35) continue;     // always out of band (compile-time)
      if ((g & 1) != wc) continue;         // parity split (wave-uniform branch)
      const int jt = g >> 1;
      const int kbase = (u * 16 + n) * KSTR + quad * 8;
      const short8 bh0 = *(const short8*)(Kh + kbase);
      const short8 bh1 = *(const short8*)(Kh + kbase + 32);
      const short8 bl0 = *(const short8*)(Kl + kbase);
      const short8 bl1 = *(const short8*)(Kl + kbase + 32);
      floatx4 c = acc[jt];
      c = __builtin_amdgcn_mfma_f32_16x16x32_bf16(bh0, ql0, c, 0, 0, 0);
      c = __builtin_amdgcn_mfma_f32_16x16x32_bf16(bl0, qh0, c, 0, 0, 0);
      c = __builtin_amdgcn_mfma_f32_16x16x32_bf16(bh0, qh0, c, 0, 0, 0);
      c = __builtin_amdgcn_mfma_f32_16x16x32_bf16(bh1, ql1, c, 0, 0, 0);
      c = __builtin_amdgcn_mfma_f32_16x16x32_bf16(bl1, qh1, c, 0, 0, 0);
      c = __builtin_amdgcn_mfma_f32_16x16x32_bf16(bh1, qh1, c, 0, 0, 0);
      acc[jt] = c;
    }
    if (m < NCH - 1) __syncthreads();
  }

  // ---- epilogue: in-lane softmax, cross-quad shfl, cross-wave LDS combine ----
  const int i     = i0 + wr * 16 + n;                       // absolute q row
  const int jbase = jb + 16 * wc + 4 * quad;                // j0 = 32*jt + jbase (mult of 4)
  const int cbase = 16 * wc + 4 * quad - 16 * wr - n - 16;  // c0 = 32*jt + cbase

  // Unmasked max: over-estimate is exact under softmax shift-invariance
  // (extra entries are real dots or staged zeros; sum excludes them below).
  float mx = acc[0][0];
#pragma unroll
  for (int jt = 0; jt < NTW; ++jt)
#pragma unroll
    for (int reg = 0; reg < 4; ++reg) mx = fmaxf(mx, acc[jt][reg]);
  mx = fmaxf(mx, __shfl_xor(mx, 16, 64));
  mx = fmaxf(mx, __shfl_xor(mx, 32, 64));
  if (quad == 0) red[0][wc][wr * 16 + n] = mx;
  __syncthreads();
  mx = fmaxf(red[0][0][wr * 16 + n], red[0][1][wr * 16 + n]);

  float sm = 0.f;
#pragma unroll
  for (int jt = 0; jt < NTW; ++jt) {
#pragma unroll
    for (int reg = 0; reg < 4; ++reg) {
      const int jj = 32 * jt + jbase + reg;
      const int cc = 32 * jt + cbase + reg;
      float e = __expf(acc[jt][reg] - mx);   // <= 1, garbage-safe
      const bool ok = ((unsigned)jj < (unsigned)S_LEN) & ((unsigned)cc <= 512u);
      e = ok ? e : 0.f;
      acc[jt][reg] = e;
      sm += e;
    }
  }
  sm += __shfl_xor(sm, 16, 64);
  sm += __shfl_xor(sm, 32, 64);
  if (quad == 0) red[1][wc][wr * 16 + n] = sm;
  __syncthreads();
  const float inv = 1.0f / (red[1][0][wr * 16 + n] + red[1][1][wr * 16 + n]);

  float* prow = out + (((size_t)(b * S_LEN + i) * NHEAD) + hh) * NC;
#pragma unroll
  for (int jt = 0; jt < NTW; ++jt) {
    const int j0 = 32 * jt + jbase;
    if ((unsigned)j0 > 4092u) continue;        // j0 % 4 == 0 -> all-or-nothing
    const int c0 = 32 * jt + cbase;
    if (c0 >= 0 && c0 <= 509) {                // full 4-wide store (dword-aligned ok)
      float4u v = {acc[jt][0] * inv, acc[jt][1] * inv,
                   acc[jt][2] * inv, acc[jt][3] * inv};
      *(float4u*)(prow + c0) = v;
    } else if (c0 > -4 && c0 < 513) {          // band-edge partial
#pragma unroll
      for (int reg = 0; reg < 4; ++reg) {
        const int cc = c0 + reg;
        if ((unsigned)cc <= 512u) prow[cc] = acc[jt][reg] * inv;
      }
    }
  }
#undef LOAD_CHUNK
#undef WRITE_CHUNK
}

extern "C" void kernel_launch(void* const* d_in, const int* in_sizes, int n_in,
                              void* d_out, int out_size, void* d_ws, size_t ws_size,
                              hipStream_t stream) {
  const float* x = (const float*)d_in[0];
  float* out = (float*)d_out;
  unsigned short* xh = (unsigned short*)d_ws;
  unsigned short* xl = xh + (size_t)32 * PV;   // 8.39M elems each (33.6 MB total)

  split_kernel<<<(32 * PV / 4) / 256, 256, 0, stream>>>(x, xh, xl);
  attn_kernel<<<32 * 128, 256, 0, stream>>>(xh, xl, out);
}